// Round 15
// baseline (1452.646 us; speedup 1.0000x reference)
//
#include <hip/hip_runtime.h>
#include <hip/hip_fp16.h>
#include <stdint.h>

#define GAS __attribute__((address_space(1)))
#define LAS __attribute__((address_space(3)))

static constexpr int K_TOT = 4096;
static constexpr int N_TOT = 4096;
static constexpr int NO_CAP = 64;   // max tracked outlier columns (actual data: 8)
static constexpr float SIGMA = 20.0f;

typedef int v4i __attribute__((ext_vector_type(4)));

// ---------------- activation: row absmax -> scale_row, int8 quant, outlier mask ----
__global__ __launch_bounds__(256) void k_quant_x(const float* __restrict__ x,
                                                 int8_t* __restrict__ qx,
                                                 float* __restrict__ scale_row,
                                                 int* __restrict__ mask) {
  const int lane = threadIdx.x & 63;
  const int wid  = threadIdx.x >> 6;
  const int m = blockIdx.x * 4 + wid;
  const float* xr = x + (size_t)m * K_TOT;

  float4 v[16];
  float amax = 0.0f;
#pragma unroll
  for (int it = 0; it < 16; ++it) {
    const int k0 = it * 256 + lane * 4;
    v[it] = *(const float4*)(xr + k0);
    const float a0 = fabsf(v[it].x), a1 = fabsf(v[it].y);
    const float a2 = fabsf(v[it].z), a3 = fabsf(v[it].w);
    amax = fmaxf(amax, fmaxf(fmaxf(a0, a1), fmaxf(a2, a3)));
    if (a0 > SIGMA) mask[k0 + 0] = 1;
    if (a1 > SIGMA) mask[k0 + 1] = 1;
    if (a2 > SIGMA) mask[k0 + 2] = 1;
    if (a3 > SIGMA) mask[k0 + 3] = 1;
  }
#pragma unroll
  for (int off = 32; off > 0; off >>= 1)
    amax = fmaxf(amax, __shfl_xor(amax, off));

  const float s = fmaxf(amax / 127.0f, 1e-8f);
  if (lane == 0) scale_row[m] = s;

  int8_t* qr = qx + (size_t)m * K_TOT;
#pragma unroll
  for (int it = 0; it < 16; ++it) {
    const int k0 = it * 256 + lane * 4;
    const int q0 = (int)rintf(fminf(fmaxf(v[it].x / s, -128.0f), 127.0f));
    const int q1 = (int)rintf(fminf(fmaxf(v[it].y / s, -128.0f), 127.0f));
    const int q2 = (int)rintf(fminf(fmaxf(v[it].z / s, -128.0f), 127.0f));
    const int q3 = (int)rintf(fminf(fmaxf(v[it].w / s, -128.0f), 127.0f));
    const uint32_t p = (uint32_t)(q0 & 0xFF) | ((uint32_t)(q1 & 0xFF) << 8) |
                       ((uint32_t)(q2 & 0xFF) << 16) | ((uint32_t)(q3 & 0xFF) << 24);
    *(uint32_t*)(qr + k0) = p;
  }
}

// ---------------- compact outlier indices (ordered, single block) ----------------
__global__ __launch_bounds__(256) void k_compact(const int* __restrict__ mask,
                                                 uint8_t* __restrict__ bitbytes,
                                                 int* __restrict__ ind,
                                                 int* __restrict__ count) {
  const int t = threadIdx.x;
  int local[16];
  int cnt = 0;
  uint32_t bits = 0;
#pragma unroll
  for (int j = 0; j < 16; ++j) {
    const int k = t * 16 + j;
    if (mask[k]) { bits |= (1u << j); local[cnt++] = k; }
  }
  bitbytes[2 * t]     = (uint8_t)(bits & 0xFF);
  bitbytes[2 * t + 1] = (uint8_t)((bits >> 8) & 0xFF);

  const int lane = t & 63, wid = t >> 6;
  int incl = cnt;
  for (int off = 1; off < 64; off <<= 1) {
    int o = __shfl_up(incl, off);
    if (lane >= off) incl += o;
  }
  __shared__ int wsum[4];
  if (lane == 63) wsum[wid] = incl;
  __syncthreads();
  int base = 0;
  for (int i = 0; i < wid; ++i) base += wsum[i];
  const int excl = base + incl - cnt;
  for (int j = 0; j < cnt; ++j) {
    const int pos = excl + j;
    if (pos < NO_CAP) ind[pos] = local[j];
  }
  if (t == 255) {
    const int tot = excl + cnt;
    *count = tot > NO_CAP ? NO_CAP : tot;
  }
}

// ---------------- fused: weight quant (blocks 0..N/4-1)  +  xo gather (rest) ----
__global__ __launch_bounds__(256) void k_quant_w_gather(const float* __restrict__ w,
                                                        const float* __restrict__ x,
                                                        const uint8_t* __restrict__ bitbytes,
                                                        const int* __restrict__ ind,
                                                        const int* __restrict__ count,
                                                        int8_t* __restrict__ qw,
                                                        float* __restrict__ scale_col,
                                                        float* __restrict__ wo,
                                                        float* __restrict__ xo,
                                                        int nwb) {
  if ((int)blockIdx.x >= nwb) {
    const int idx = (blockIdx.x - nwb) * 256 + threadIdx.x;   // over M * NO_CAP
    const int m = idx >> 6, j = idx & 63;
    const int cnt = *count;
    float val = 0.0f;
    if (j < cnt) val = x[(size_t)m * K_TOT + ind[j]];
    xo[(size_t)m * NO_CAP + j] = val;
    return;
  }
  const int lane = threadIdx.x & 63;
  const int wid  = threadIdx.x >> 6;
  const int n = blockIdx.x * 4 + wid;
  const float* wr_ = w + (size_t)n * K_TOT;

  float4 v[16];
  float amax = 0.0f;
#pragma unroll
  for (int it = 0; it < 16; ++it) {
    const int k0 = it * 256 + lane * 4;
    v[it] = *(const float4*)(wr_ + k0);
    const uint32_t b = (uint32_t)(bitbytes[k0 >> 3] >> (k0 & 7));
    if (b & 1u) v[it].x = 0.0f;
    if (b & 2u) v[it].y = 0.0f;
    if (b & 4u) v[it].z = 0.0f;
    if (b & 8u) v[it].w = 0.0f;
    amax = fmaxf(amax, fmaxf(fmaxf(fabsf(v[it].x), fabsf(v[it].y)),
                             fmaxf(fabsf(v[it].z), fabsf(v[it].w))));
  }
#pragma unroll
  for (int off = 32; off > 0; off >>= 1)
    amax = fmaxf(amax, __shfl_xor(amax, off));

  float s = amax / 127.0f;
  s = __half2float(__float2half_rn(s));
  s = fmaxf(s, 1e-8f);
  if (lane == 0) scale_col[n] = s;

  int8_t* qr = qw + (size_t)n * K_TOT;
#pragma unroll
  for (int it = 0; it < 16; ++it) {
    const int k0 = it * 256 + lane * 4;
    const int q0 = (int)rintf(fminf(fmaxf(v[it].x / s, -128.0f), 127.0f));
    const int q1 = (int)rintf(fminf(fmaxf(v[it].y / s, -128.0f), 127.0f));
    const int q2 = (int)rintf(fminf(fmaxf(v[it].z / s, -128.0f), 127.0f));
    const int q3 = (int)rintf(fminf(fmaxf(v[it].w / s, -128.0f), 127.0f));
    const uint32_t p = (uint32_t)(q0 & 0xFF) | ((uint32_t)(q1 & 0xFF) << 8) |
                       ((uint32_t)(q2 & 0xFF) << 16) | ((uint32_t)(q3 & 0xFF) << 24);
    *(uint32_t*)(qr + k0) = p;
  }

  const int cnt = *count;
  if (lane < NO_CAP) {
    float val = 0.0f;
    if (lane < cnt) val = wr_[ind[lane]];
    wo[(size_t)n * NO_CAP + lane] = val;
  }
}

// =====================================================================
// int8 GEMM — ROUND-15: 2 BLOCKS/CU. BK 128->64, dbuf LDS 64 KB (A 2x16KB
// + B 2x16KB) -> two co-resident 8-wave blocks (launch_bounds(512,4)).
// Mechanism under test: all r9-r14 configs pinned at ~10.2 B/cyc/CU
// global_load_lds fill (r2 too); m201 sustains ~20 on the same path.
// Co-residency doubles outstanding DMA streams/CU + m114 cross-block
// MFMA/VMEM overlap. 64 K-tiles, 2 phases each (r14 skeleton):
//   A: 12 ds_reads -> bar -> 16 MFMA (rows 0-3)
//   B: stage t+2 (4 loads) -> vmcnt(4) -> bar -> 16 MFMA (rows 4-7)
// LDS rows now 64 B; swizzle chunk^((row>>1)&3) (2-way worst = free),
// applied both sides (pre-swizzled global source + swizzled ds_read).
// Keeps r13: 8x8 supertile map, fused pre-kernels, NT stores.
// =====================================================================
// one global_load_lds per thread covers an 8 KB half-tile (512 x 16B)
#define STAGE_A(h, kt, bufb) \
  __builtin_amdgcn_global_load_lds((const GAS void*)(qx + gAoff + (size_t)(h)*128*K_TOT + (size_t)(kt)*64), \
      (LAS void*)(smem + (bufb)*16384 + (h)*8192 + ldsOffW), 16, 0, 0)

#define STAGE_B(h, kt, bufb) \
  __builtin_amdgcn_global_load_lds((const GAS void*)(qw + gBoff + (size_t)(h)*128*K_TOT + (size_t)(kt)*64), \
      (LAS void*)(smem + 32768 + (bufb)*16384 + (h)*8192 + ldsOffW), 16, 0, 0)

#define LDA(mq, bufb) do { \
  _Pragma("unroll") for (int i_ = 0; i_ < 4; ++i_) \
    a[(mq)*4 + i_] = *(const v4i*)(smem + aHalfBase + (bufb)*16384 + ((mq)*4 + i_)*1024 + rcSwz); \
} while (0)

#define LDB(dst, nq, bufb) do { \
  _Pragma("unroll") for (int i_ = 0; i_ < 2; ++i_) \
    dst[i_] = *(const v4i*)(smem + bHalfBase + (bufb)*16384 + (bColBlk + (nq)*2 + i_)*1024 + rcSwz); \
} while (0)

#define MM(mq, nq, bsrc) do { \
  _Pragma("unroll") for (int i_ = 0; i_ < 4; ++i_) \
  _Pragma("unroll") for (int j_ = 0; j_ < 2; ++j_) \
    acc[(mq)*4 + i_][(nq)*2 + j_] = __builtin_amdgcn_mfma_i32_16x16x64_i8( \
        a[(mq)*4 + i_], bsrc[j_], acc[(mq)*4 + i_][(nq)*2 + j_], 0, 0, 0); \
} while (0)

#define BAR() __builtin_amdgcn_s_barrier()

__global__ __launch_bounds__(512, 4) void k_gemm8(const int8_t* __restrict__ qx,
                                                  const int8_t* __restrict__ qw,
                                                  const float* __restrict__ scale_row,
                                                  const float* __restrict__ scale_col,
                                                  const float* __restrict__ xo,
                                                  const float* __restrict__ wo,
                                                  const int* __restrict__ countp,
                                                  const float* __restrict__ bias,
                                                  float* __restrict__ out) {
  extern __shared__ int8_t smem[];
  constexpr int NT = K_TOT / 64;   // 64 K-tiles

  const int t = threadIdx.x;
  const int lane = t & 63;
  const int wid = t >> 6;
  const int wm = wid >> 2;          // 0..1
  const int wn = wid & 3;           // 0..3

  // 8x8 supertile dispatch mapping (bijective: nbx=32, nby=16, both %8==0)
  const int nbx = gridDim.x;                       // M/256 (32)
  const int o = blockIdx.y * nbx + blockIdx.x;     // dispatch order
  const int gm_cnt = nbx >> 3;                     // supergroups along m (4)
  const int g = o >> 6, r = o & 63;
  const int bm0 = (((g % gm_cnt) << 3) + (r & 7)) * 256;
  const int bn0 = (((g / gm_cnt) << 3) + (r >> 3)) * 256;

  // staging address: thread t covers 16B chunk (t&3) of 64B row (t>>2) of an
  // 8 KB half-tile; source chunk pre-swizzled ^((row>>1)&3) within the row
  const int sRow = t >> 2, sCh = t & 3;
  const int sChS = sCh ^ ((sRow >> 1) & 3);
  const size_t gAoff = (size_t)(bm0 + sRow) * K_TOT + (size_t)(sChS * 16);
  const size_t gBoff = (size_t)(bn0 + sRow) * K_TOT + (size_t)(sChS * 16);
  const int ldsOffW = wid * 1024;          // wave-uniform; lane*16 added by HW

  // ds_read fragment addressing (swizzled): row rr=lane&15, chunk q=lane>>4
  const int rr = lane & 15;
  const int q  = lane >> 4;
  const int rcSwz = rr * 64 + ((q ^ ((rr >> 1) & 3)) * 16);
  const int aHalfBase = wm * 8192;
  const int bHalfBase = 32768 + (wn >> 1) * 8192;
  const int bColBlk = (wn & 1) * 4;

  v4i acc[8][4];
#pragma unroll
  for (int i = 0; i < 8; ++i)
#pragma unroll
    for (int j = 0; j < 4; ++j) acc[i][j] = (v4i){0, 0, 0, 0};
  v4i a[8], b0[2], b1[2];

  // prologue: stage tile0 -> buf0, tile1 -> buf1 (4 loads each); t0 done at vmcnt(4)
  STAGE_A(0, 0, 0);
  STAGE_A(1, 0, 0);
  STAGE_B(0, 0, 0);
  STAGE_B(1, 0, 0);
  STAGE_A(0, 1, 1);
  STAGE_A(1, 1, 1);
  STAGE_B(0, 1, 1);
  STAGE_B(1, 1, 1);
  asm volatile("s_waitcnt vmcnt(4)" ::: "memory");
  BAR();

#pragma unroll 2
  for (int t0 = 0; t0 < NT; ++t0) {
    const int buf = t0 & 1;
    // ---- phase A: all 12 reads ; 16 MFMA (acc rows 0-3) ----
    LDA(0, buf);
    LDB(b0, 0, buf);
    LDB(b1, 1, buf);
    LDA(1, buf);
    BAR();
    __builtin_amdgcn_s_setprio(1);
    MM(0, 0, b0);
    MM(0, 1, b1);
    __builtin_amdgcn_s_setprio(0);
    // ---- phase B: stage tile t+2 -> same-parity buffer ; retire t+1 ;
    //      16 MFMA (acc rows 4-7) ----
    if (t0 + 2 < NT) {
      STAGE_A(0, t0 + 2, buf);
      STAGE_A(1, t0 + 2, buf);
      STAGE_B(0, t0 + 2, buf);
      STAGE_B(1, t0 + 2, buf);
    }
    if (t0 < NT - 2) {
      asm volatile("s_waitcnt vmcnt(4)" ::: "memory");
    } else {
      asm volatile("s_waitcnt vmcnt(0)" ::: "memory");
    }
    BAR();
    __builtin_amdgcn_s_setprio(1);
    MM(1, 1, b1);
    MM(1, 0, b0);
    __builtin_amdgcn_s_setprio(0);
  }

  // ---- epilogue: y = acc*sr*sc + outlier_dot + bias, rounded to fp16 precision ----
  const int cnt = *countp;
  const int col = lane & 15;
  const int row4 = (lane >> 4) * 4;

  float scn[4], bzn[4];
  int nn[4];
#pragma unroll
  for (int ni = 0; ni < 4; ++ni) {
    const int n = bn0 + wn * 64 + ni * 16 + col;
    nn[ni] = n;
    scn[ni] = scale_col[n];
    bzn[ni] = bias[n];
  }

  if (cnt <= 8) {
    float wv[4][8];
#pragma unroll
    for (int ni = 0; ni < 4; ++ni)
#pragma unroll
      for (int j = 0; j < 8; ++j) wv[ni][j] = wo[(size_t)nn[ni] * NO_CAP + j];
#pragma unroll
    for (int mi = 0; mi < 8; ++mi) {
#pragma unroll
      for (int r2 = 0; r2 < 4; ++r2) {
        const int m = bm0 + wm * 128 + mi * 16 + row4 + r2;
        const float srm = scale_row[m];
        float xv[8];
#pragma unroll
        for (int j = 0; j < 8; ++j) xv[j] = xo[(size_t)m * NO_CAP + j];
#pragma unroll
        for (int ni = 0; ni < 4; ++ni) {
          float y = (float)acc[mi][ni][r2] * srm * scn[ni];
#pragma unroll
          for (int j = 0; j < 8; ++j) y += xv[j] * wv[ni][j];
          y += bzn[ni];
          __builtin_nontemporal_store(__half2float(__float2half_rn(y)),
                                      &out[(size_t)m * N_TOT + nn[ni]]);
        }
      }
    }
  } else {
#pragma unroll
    for (int mi = 0; mi < 8; ++mi) {
#pragma unroll
      for (int r2 = 0; r2 < 4; ++r2) {
        const int m = bm0 + wm * 128 + mi * 16 + row4 + r2;
        const float srm = scale_row[m];
#pragma unroll
        for (int ni = 0; ni < 4; ++ni) {
          float y = (float)acc[mi][ni][r2] * srm * scn[ni];
          for (int j = 0; j < cnt; ++j)
            y += xo[(size_t)m * NO_CAP + j] * wo[(size_t)nn[ni] * NO_CAP + j];
          y += bzn[ni];
          __builtin_nontemporal_store(__half2float(__float2half_rn(y)),
                                      &out[(size_t)m * N_TOT + nn[ni]]);
        }
      }
    }
  }
}

extern "C" void kernel_launch(void* const* d_in, const int* in_sizes, int n_in,
                              void* d_out, int out_size, void* d_ws, size_t ws_size,
                              hipStream_t stream) {
  const float* x    = (const float*)d_in[0];
  const float* w    = (const float*)d_in[1];
  const float* bias = (const float*)d_in[2];
  float* out        = (float*)d_out;

  const int M = in_sizes[0] / K_TOT;   // 8192 for B=4,S=2048

  char* ws = (char*)d_ws;
  const size_t OFF_SR   = 0;
  const size_t OFF_SC   = OFF_SR + sizeof(float) * (size_t)M;
  const size_t OFF_MASK = OFF_SC + sizeof(float) * (size_t)N_TOT;
  const size_t OFF_IND  = OFF_MASK + sizeof(int) * (size_t)K_TOT;
  const size_t OFF_CNT  = OFF_IND + sizeof(int) * (size_t)NO_CAP;
  const size_t OFF_BB   = OFF_CNT + 256;
  const size_t OFF_XO   = (OFF_BB + (size_t)(K_TOT / 8) + 255) & ~(size_t)255;
  const size_t OFF_WO   = OFF_XO + sizeof(float) * (size_t)M * NO_CAP;
  const size_t OFF_QX   = (OFF_WO + sizeof(float) * (size_t)N_TOT * NO_CAP + 255) & ~(size_t)255;
  const size_t OFF_QW   = OFF_QX + (size_t)M * K_TOT;

  float* scale_row  = (float*)(ws + OFF_SR);
  float* scale_col  = (float*)(ws + OFF_SC);
  int* mask         = (int*)(ws + OFF_MASK);
  int* ind          = (int*)(ws + OFF_IND);
  int* count        = (int*)(ws + OFF_CNT);
  uint8_t* bitbytes = (uint8_t*)(ws + OFF_BB);
  float* xo         = (float*)(ws + OFF_XO);
  float* wo         = (float*)(ws + OFF_WO);
  int8_t* qx        = (int8_t*)(ws + OFF_QX);
  int8_t* qw        = (int8_t*)(ws + OFF_QW);

  // 64 KiB dynamic LDS -> 2 blocks/CU
  hipFuncSetAttribute((const void*)k_gemm8,
                      hipFuncAttributeMaxDynamicSharedMemorySize, 65536);

  hipMemsetAsync(mask, 0, sizeof(int) * (size_t)K_TOT, stream);
  hipLaunchKernelGGL(k_quant_x, dim3(M / 4), dim3(256), 0, stream, x, qx, scale_row, mask);
  hipLaunchKernelGGL(k_compact, dim3(1), dim3(256), 0, stream, mask, bitbytes, ind, count);
  const int nwb = N_TOT / 4;                         // 1024 weight blocks
  const int ngb = (M * NO_CAP) / 256;                // 2048 gather blocks
  hipLaunchKernelGGL(k_quant_w_gather, dim3(nwb + ngb), dim3(256), 0, stream,
                     w, x, bitbytes, ind, count, qw, scale_col, wo, xo, nwb);
  hipLaunchKernelGGL(k_gemm8, dim3(M / 256, N_TOT / 256), dim3(512), 65536, stream,
                     qx, qw, scale_row, scale_col, xo, wo, count, bias, out);
}

// Round 16
// 595.499 us; speedup vs baseline: 2.4394x; 2.4394x over previous
//
#include <hip/hip_runtime.h>
#include <hip/hip_fp16.h>
#include <stdint.h>

#define GAS __attribute__((address_space(1)))
#define LAS __attribute__((address_space(3)))

static constexpr int K_TOT = 4096;
static constexpr int N_TOT = 4096;
static constexpr int NO_CAP = 64;   // max tracked outlier columns (actual data: 8)
static constexpr float SIGMA = 20.0f;

typedef int v4i __attribute__((ext_vector_type(4)));

// ---------------- activation: row absmax -> scale_row, int8 quant, outlier mask ----
__global__ __launch_bounds__(256) void k_quant_x(const float* __restrict__ x,
                                                 int8_t* __restrict__ qx,
                                                 float* __restrict__ scale_row,
                                                 int* __restrict__ mask) {
  const int lane = threadIdx.x & 63;
  const int wid  = threadIdx.x >> 6;
  const int m = blockIdx.x * 4 + wid;
  const float* xr = x + (size_t)m * K_TOT;

  float4 v[16];
  float amax = 0.0f;
#pragma unroll
  for (int it = 0; it < 16; ++it) {
    const int k0 = it * 256 + lane * 4;
    v[it] = *(const float4*)(xr + k0);
    const float a0 = fabsf(v[it].x), a1 = fabsf(v[it].y);
    const float a2 = fabsf(v[it].z), a3 = fabsf(v[it].w);
    amax = fmaxf(amax, fmaxf(fmaxf(a0, a1), fmaxf(a2, a3)));
    if (a0 > SIGMA) mask[k0 + 0] = 1;
    if (a1 > SIGMA) mask[k0 + 1] = 1;
    if (a2 > SIGMA) mask[k0 + 2] = 1;
    if (a3 > SIGMA) mask[k0 + 3] = 1;
  }
#pragma unroll
  for (int off = 32; off > 0; off >>= 1)
    amax = fmaxf(amax, __shfl_xor(amax, off));

  const float s = fmaxf(amax / 127.0f, 1e-8f);
  if (lane == 0) scale_row[m] = s;

  int8_t* qr = qx + (size_t)m * K_TOT;
#pragma unroll
  for (int it = 0; it < 16; ++it) {
    const int k0 = it * 256 + lane * 4;
    const int q0 = (int)rintf(fminf(fmaxf(v[it].x / s, -128.0f), 127.0f));
    const int q1 = (int)rintf(fminf(fmaxf(v[it].y / s, -128.0f), 127.0f));
    const int q2 = (int)rintf(fminf(fmaxf(v[it].z / s, -128.0f), 127.0f));
    const int q3 = (int)rintf(fminf(fmaxf(v[it].w / s, -128.0f), 127.0f));
    const uint32_t p = (uint32_t)(q0 & 0xFF) | ((uint32_t)(q1 & 0xFF) << 8) |
                       ((uint32_t)(q2 & 0xFF) << 16) | ((uint32_t)(q3 & 0xFF) << 24);
    *(uint32_t*)(qr + k0) = p;
  }
}

// ---------------- compact outlier indices (ordered, single block) ----------------
__global__ __launch_bounds__(256) void k_compact(const int* __restrict__ mask,
                                                 uint8_t* __restrict__ bitbytes,
                                                 int* __restrict__ ind,
                                                 int* __restrict__ count) {
  const int t = threadIdx.x;
  int local[16];
  int cnt = 0;
  uint32_t bits = 0;
#pragma unroll
  for (int j = 0; j < 16; ++j) {
    const int k = t * 16 + j;
    if (mask[k]) { bits |= (1u << j); local[cnt++] = k; }
  }
  bitbytes[2 * t]     = (uint8_t)(bits & 0xFF);
  bitbytes[2 * t + 1] = (uint8_t)((bits >> 8) & 0xFF);

  const int lane = t & 63, wid = t >> 6;
  int incl = cnt;
  for (int off = 1; off < 64; off <<= 1) {
    int o = __shfl_up(incl, off);
    if (lane >= off) incl += o;
  }
  __shared__ int wsum[4];
  if (lane == 63) wsum[wid] = incl;
  __syncthreads();
  int base = 0;
  for (int i = 0; i < wid; ++i) base += wsum[i];
  const int excl = base + incl - cnt;
  for (int j = 0; j < cnt; ++j) {
    const int pos = excl + j;
    if (pos < NO_CAP) ind[pos] = local[j];
  }
  if (t == 255) {
    const int tot = excl + cnt;
    *count = tot > NO_CAP ? NO_CAP : tot;
  }
}

// ---------------- fused: weight quant (blocks 0..N/4-1)  +  xo gather (rest) ----
__global__ __launch_bounds__(256) void k_quant_w_gather(const float* __restrict__ w,
                                                        const float* __restrict__ x,
                                                        const uint8_t* __restrict__ bitbytes,
                                                        const int* __restrict__ ind,
                                                        const int* __restrict__ count,
                                                        int8_t* __restrict__ qw,
                                                        float* __restrict__ scale_col,
                                                        float* __restrict__ wo,
                                                        float* __restrict__ xo,
                                                        int nwb) {
  if ((int)blockIdx.x >= nwb) {
    const int idx = (blockIdx.x - nwb) * 256 + threadIdx.x;   // over M * NO_CAP
    const int m = idx >> 6, j = idx & 63;
    const int cnt = *count;
    float val = 0.0f;
    if (j < cnt) val = x[(size_t)m * K_TOT + ind[j]];
    xo[(size_t)m * NO_CAP + j] = val;
    return;
  }
  const int lane = threadIdx.x & 63;
  const int wid  = threadIdx.x >> 6;
  const int n = blockIdx.x * 4 + wid;
  const float* wr_ = w + (size_t)n * K_TOT;

  float4 v[16];
  float amax = 0.0f;
#pragma unroll
  for (int it = 0; it < 16; ++it) {
    const int k0 = it * 256 + lane * 4;
    v[it] = *(const float4*)(wr_ + k0);
    const uint32_t b = (uint32_t)(bitbytes[k0 >> 3] >> (k0 & 7));
    if (b & 1u) v[it].x = 0.0f;
    if (b & 2u) v[it].y = 0.0f;
    if (b & 4u) v[it].z = 0.0f;
    if (b & 8u) v[it].w = 0.0f;
    amax = fmaxf(amax, fmaxf(fmaxf(fabsf(v[it].x), fabsf(v[it].y)),
                             fmaxf(fabsf(v[it].z), fabsf(v[it].w))));
  }
#pragma unroll
  for (int off = 32; off > 0; off >>= 1)
    amax = fmaxf(amax, __shfl_xor(amax, off));

  float s = amax / 127.0f;
  s = __half2float(__float2half_rn(s));
  s = fmaxf(s, 1e-8f);
  if (lane == 0) scale_col[n] = s;

  int8_t* qr = qw + (size_t)n * K_TOT;
#pragma unroll
  for (int it = 0; it < 16; ++it) {
    const int k0 = it * 256 + lane * 4;
    const int q0 = (int)rintf(fminf(fmaxf(v[it].x / s, -128.0f), 127.0f));
    const int q1 = (int)rintf(fminf(fmaxf(v[it].y / s, -128.0f), 127.0f));
    const int q2 = (int)rintf(fminf(fmaxf(v[it].z / s, -128.0f), 127.0f));
    const int q3 = (int)rintf(fminf(fmaxf(v[it].w / s, -128.0f), 127.0f));
    const uint32_t p = (uint32_t)(q0 & 0xFF) | ((uint32_t)(q1 & 0xFF) << 8) |
                       ((uint32_t)(q2 & 0xFF) << 16) | ((uint32_t)(q3 & 0xFF) << 24);
    *(uint32_t*)(qr + k0) = p;
  }

  const int cnt = *count;
  if (lane < NO_CAP) {
    float val = 0.0f;
    if (lane < cnt) val = wr_[ind[lane]];
    wo[(size_t)n * NO_CAP + lane] = val;
  }
}

// =====================================================================
// int8 GEMM — ROUND-16: 16-WAVE BLOCK, 4 waves/SIMD (proper MLP test).
// r15 lesson: launch_bounds 2nd arg caps UNIFIED regs at 512/N per wave;
// acc must shrink to fit. Here: 1024 threads = 16 waves (4M x 4N), each
// owning 64x64 -> acc[4][4] = 64 AGPR; a[4]+b[4] = 32; ~120 total <= 128
// cap of __launch_bounds__(1024,4). Tile stays 256x256 (same 1.05 GB
// staged, same reuse); BK=64; LDS 64 KB dbuf (A 2x16KB @0, B 2x16KB
// @32768). Per tile: 1 A-load + 1 B-load per thread (2 streams), stage
// t+2 in phase B, steady vmcnt(2), tail vmcnt(0).
// Swizzle: 64B rows, source chunk ^((row>>1)&3), read chunk q^((rr>>1)&3)
// — both-sides (rule #21); quarter-wave bank analysis = 2-way (free),
// r15 measured 0 conflicts with this exact pattern.
// Keeps r13: 8x8 supertile map, fused pre-kernels, NT stores.
// =====================================================================
#define STAGE_A(kt, bufb) \
  __builtin_amdgcn_global_load_lds((const GAS void*)(qx + gAoff + (size_t)(kt)*64), \
      (LAS void*)(smem + (bufb)*16384 + ldsOffW), 16, 0, 0)

#define STAGE_B(kt, bufb) \
  __builtin_amdgcn_global_load_lds((const GAS void*)(qw + gBoff + (size_t)(kt)*64), \
      (LAS void*)(smem + 32768 + (bufb)*16384 + ldsOffW), 16, 0, 0)

#define LDA(bufb) do { \
  _Pragma("unroll") for (int i_ = 0; i_ < 4; ++i_) \
    a[i_] = *(const v4i*)(smem + (bufb)*16384 + aRow + i_*1024); \
} while (0)

#define LDB(bufb) do { \
  _Pragma("unroll") for (int i_ = 0; i_ < 4; ++i_) \
    b[i_] = *(const v4i*)(smem + 32768 + (bufb)*16384 + bRow + i_*1024); \
} while (0)

#define MM2(n0, n1) do { \
  _Pragma("unroll") for (int i_ = 0; i_ < 4; ++i_) { \
    acc[i_][n0] = __builtin_amdgcn_mfma_i32_16x16x64_i8(a[i_], b[n0], acc[i_][n0], 0, 0, 0); \
    acc[i_][n1] = __builtin_amdgcn_mfma_i32_16x16x64_i8(a[i_], b[n1], acc[i_][n1], 0, 0, 0); \
  } \
} while (0)

#define BAR() __builtin_amdgcn_s_barrier()

__global__ __launch_bounds__(1024, 4) void k_gemm16(const int8_t* __restrict__ qx,
                                                    const int8_t* __restrict__ qw,
                                                    const float* __restrict__ scale_row,
                                                    const float* __restrict__ scale_col,
                                                    const float* __restrict__ xo,
                                                    const float* __restrict__ wo,
                                                    const int* __restrict__ countp,
                                                    const float* __restrict__ bias,
                                                    float* __restrict__ out) {
  extern __shared__ int8_t smem[];
  constexpr int NT = K_TOT / 64;   // 64 K-tiles

  const int t = threadIdx.x;
  const int lane = t & 63;
  const int wid = t >> 6;          // 0..15
  const int wm = wid >> 2;         // 0..3
  const int wn = wid & 3;          // 0..3

  // 8x8 supertile dispatch mapping (bijective: nbx=32, nby=16, both %8==0)
  const int nbx = gridDim.x;                       // M/256 (32)
  const int o = blockIdx.y * nbx + blockIdx.x;     // dispatch order
  const int gm_cnt = nbx >> 3;                     // supergroups along m (4)
  const int g = o >> 6, r = o & 63;
  const int bm0 = (((g % gm_cnt) << 3) + (r & 7)) * 256;
  const int bn0 = (((g / gm_cnt) << 3) + (r >> 3)) * 256;

  // staging: thread t covers 16B chunk (t&3) of 64B row (t>>2) of a 16KB tile
  const int sRow = t >> 2, sCh = t & 3;
  const int sChS = sCh ^ ((sRow >> 1) & 3);        // pre-swizzled source chunk
  const size_t gAoff = (size_t)(bm0 + sRow) * K_TOT + (size_t)(sChS * 16);
  const size_t gBoff = (size_t)(bn0 + sRow) * K_TOT + (size_t)(sChS * 16);
  const int ldsOffW = wid * 1024;                  // wave-uniform; lane*16 added by HW

  // ds_read fragment addressing (swizzled): row rr=lane&15, chunk q=lane>>4
  const int rr = lane & 15;
  const int q  = lane >> 4;
  const int cSw = (q ^ ((rr >> 1) & 3)) * 16;
  const int aRow = (wm * 64 + rr) * 64 + cSw;      // + mi*1024
  const int bRow = (wn * 64 + rr) * 64 + cSw;      // + ni*1024

  v4i acc[4][4];
#pragma unroll
  for (int i = 0; i < 4; ++i)
#pragma unroll
    for (int j = 0; j < 4; ++j) acc[i][j] = (v4i){0, 0, 0, 0};
  v4i a[4], b[4];

  // prologue: stage tile0 -> buf0, tile1 -> buf1 (2 loads each)
  STAGE_A(0, 0);
  STAGE_B(0, 0);
  STAGE_A(1, 1);
  STAGE_B(1, 1);
  asm volatile("s_waitcnt vmcnt(2)" ::: "memory");
  BAR();

#pragma unroll 2
  for (int t0 = 0; t0 < NT; ++t0) {
    const int buf = t0 & 1;
    // ---- phase A: all 8 frag reads ; 8 MFMA (n-cols 0,1) ----
    LDA(buf);
    LDB(buf);
    BAR();
    __builtin_amdgcn_s_setprio(1);
    MM2(0, 1);
    __builtin_amdgcn_s_setprio(0);
    // ---- phase B: stage tile t+2 -> same-parity buffer ; retire t+1 ;
    //      8 MFMA (n-cols 2,3) ----
    if (t0 + 2 < NT) {
      STAGE_A(t0 + 2, buf);
      STAGE_B(t0 + 2, buf);
    }
    if (t0 < NT - 2) {
      asm volatile("s_waitcnt vmcnt(2)" ::: "memory");
    } else {
      asm volatile("s_waitcnt vmcnt(0)" ::: "memory");
    }
    BAR();
    __builtin_amdgcn_s_setprio(1);
    MM2(2, 3);
    __builtin_amdgcn_s_setprio(0);
  }

  // ---- epilogue (low-pressure: wo loaded inline): y = acc*sr*sc + outl + bias ----
  const int cnt = *countp;
  const int col = lane & 15;
  const int row4 = (lane >> 4) * 4;

  float scn[4], bzn[4];
  int nn[4];
#pragma unroll
  for (int ni = 0; ni < 4; ++ni) {
    const int n = bn0 + wn * 64 + ni * 16 + col;
    nn[ni] = n;
    scn[ni] = scale_col[n];
    bzn[ni] = bias[n];
  }

  if (cnt <= 8) {
#pragma unroll
    for (int mi = 0; mi < 4; ++mi) {
#pragma unroll
      for (int r2 = 0; r2 < 4; ++r2) {
        const int m = bm0 + wm * 64 + mi * 16 + row4 + r2;
        const float srm = scale_row[m];
        float xv[8];
#pragma unroll
        for (int j = 0; j < 8; ++j) xv[j] = xo[(size_t)m * NO_CAP + j];
#pragma unroll
        for (int ni = 0; ni < 4; ++ni) {
          const float* wv = wo + (size_t)nn[ni] * NO_CAP;
          float y = (float)acc[mi][ni][r2] * srm * scn[ni];
#pragma unroll
          for (int j = 0; j < 8; ++j) y += xv[j] * wv[j];
          y += bzn[ni];
          __builtin_nontemporal_store(__half2float(__float2half_rn(y)),
                                      &out[(size_t)m * N_TOT + nn[ni]]);
        }
      }
    }
  } else {
#pragma unroll
    for (int mi = 0; mi < 4; ++mi) {
#pragma unroll
      for (int r2 = 0; r2 < 4; ++r2) {
        const int m = bm0 + wm * 64 + mi * 16 + row4 + r2;
        const float srm = scale_row[m];
#pragma unroll
        for (int ni = 0; ni < 4; ++ni) {
          const float* wv = wo + (size_t)nn[ni] * NO_CAP;
          float y = (float)acc[mi][ni][r2] * srm * scn[ni];
          for (int j = 0; j < cnt; ++j)
            y += xo[(size_t)m * NO_CAP + j] * wv[j];
          y += bzn[ni];
          __builtin_nontemporal_store(__half2float(__float2half_rn(y)),
                                      &out[(size_t)m * N_TOT + nn[ni]]);
        }
      }
    }
  }
}

extern "C" void kernel_launch(void* const* d_in, const int* in_sizes, int n_in,
                              void* d_out, int out_size, void* d_ws, size_t ws_size,
                              hipStream_t stream) {
  const float* x    = (const float*)d_in[0];
  const float* w    = (const float*)d_in[1];
  const float* bias = (const float*)d_in[2];
  float* out        = (float*)d_out;

  const int M = in_sizes[0] / K_TOT;   // 8192 for B=4,S=2048

  char* ws = (char*)d_ws;
  const size_t OFF_SR   = 0;
  const size_t OFF_SC   = OFF_SR + sizeof(float) * (size_t)M;
  const size_t OFF_MASK = OFF_SC + sizeof(float) * (size_t)N_TOT;
  const size_t OFF_IND  = OFF_MASK + sizeof(int) * (size_t)K_TOT;
  const size_t OFF_CNT  = OFF_IND + sizeof(int) * (size_t)NO_CAP;
  const size_t OFF_BB   = OFF_CNT + 256;
  const size_t OFF_XO   = (OFF_BB + (size_t)(K_TOT / 8) + 255) & ~(size_t)255;
  const size_t OFF_WO   = OFF_XO + sizeof(float) * (size_t)M * NO_CAP;
  const size_t OFF_QX   = (OFF_WO + sizeof(float) * (size_t)N_TOT * NO_CAP + 255) & ~(size_t)255;
  const size_t OFF_QW   = OFF_QX + (size_t)M * K_TOT;

  float* scale_row  = (float*)(ws + OFF_SR);
  float* scale_col  = (float*)(ws + OFF_SC);
  int* mask         = (int*)(ws + OFF_MASK);
  int* ind          = (int*)(ws + OFF_IND);
  int* count        = (int*)(ws + OFF_CNT);
  uint8_t* bitbytes = (uint8_t*)(ws + OFF_BB);
  float* xo         = (float*)(ws + OFF_XO);
  float* wo         = (float*)(ws + OFF_WO);
  int8_t* qx        = (int8_t*)(ws + OFF_QX);
  int8_t* qw        = (int8_t*)(ws + OFF_QW);

  // 64 KiB dynamic LDS
  hipFuncSetAttribute((const void*)k_gemm16,
                      hipFuncAttributeMaxDynamicSharedMemorySize, 65536);

  hipMemsetAsync(mask, 0, sizeof(int) * (size_t)K_TOT, stream);
  hipLaunchKernelGGL(k_quant_x, dim3(M / 4), dim3(256), 0, stream, x, qx, scale_row, mask);
  hipLaunchKernelGGL(k_compact, dim3(1), dim3(256), 0, stream, mask, bitbytes, ind, count);
  const int nwb = N_TOT / 4;                         // 1024 weight blocks
  const int ngb = (M * NO_CAP) / 256;                // 2048 gather blocks
  hipLaunchKernelGGL(k_quant_w_gather, dim3(nwb + ngb), dim3(256), 0, stream,
                     w, x, bitbytes, ind, count, qw, scale_col, wo, xo, nwb);
  hipLaunchKernelGGL(k_gemm16, dim3(M / 256, N_TOT / 256), dim3(1024), 65536, stream,
                     qx, qw, scale_row, scale_col, xo, wo, count, bias, out);
}

// Round 17
// 223.354 us; speedup vs baseline: 6.5038x; 2.6662x over previous
//
#include <hip/hip_runtime.h>
#include <hip/hip_fp16.h>
#include <stdint.h>

#define GAS __attribute__((address_space(1)))
#define LAS __attribute__((address_space(3)))

static constexpr int K_TOT = 4096;
static constexpr int N_TOT = 4096;
static constexpr int NO_CAP = 64;   // max tracked outlier columns (actual data: 8)
static constexpr float SIGMA = 20.0f;

typedef int v4i __attribute__((ext_vector_type(4)));

// ---------------- activation: row absmax -> scale_row, int8 quant, outlier mask ----
__global__ __launch_bounds__(256) void k_quant_x(const float* __restrict__ x,
                                                 int8_t* __restrict__ qx,
                                                 float* __restrict__ scale_row,
                                                 int* __restrict__ mask) {
  const int lane = threadIdx.x & 63;
  const int wid  = threadIdx.x >> 6;
  const int m = blockIdx.x * 4 + wid;
  const float* xr = x + (size_t)m * K_TOT;

  float4 v[16];
  float amax = 0.0f;
#pragma unroll
  for (int it = 0; it < 16; ++it) {
    const int k0 = it * 256 + lane * 4;
    v[it] = *(const float4*)(xr + k0);
    const float a0 = fabsf(v[it].x), a1 = fabsf(v[it].y);
    const float a2 = fabsf(v[it].z), a3 = fabsf(v[it].w);
    amax = fmaxf(amax, fmaxf(fmaxf(a0, a1), fmaxf(a2, a3)));
    if (a0 > SIGMA) mask[k0 + 0] = 1;
    if (a1 > SIGMA) mask[k0 + 1] = 1;
    if (a2 > SIGMA) mask[k0 + 2] = 1;
    if (a3 > SIGMA) mask[k0 + 3] = 1;
  }
#pragma unroll
  for (int off = 32; off > 0; off >>= 1)
    amax = fmaxf(amax, __shfl_xor(amax, off));

  const float s = fmaxf(amax / 127.0f, 1e-8f);
  if (lane == 0) scale_row[m] = s;

  int8_t* qr = qx + (size_t)m * K_TOT;
#pragma unroll
  for (int it = 0; it < 16; ++it) {
    const int k0 = it * 256 + lane * 4;
    const int q0 = (int)rintf(fminf(fmaxf(v[it].x / s, -128.0f), 127.0f));
    const int q1 = (int)rintf(fminf(fmaxf(v[it].y / s, -128.0f), 127.0f));
    const int q2 = (int)rintf(fminf(fmaxf(v[it].z / s, -128.0f), 127.0f));
    const int q3 = (int)rintf(fminf(fmaxf(v[it].w / s, -128.0f), 127.0f));
    const uint32_t p = (uint32_t)(q0 & 0xFF) | ((uint32_t)(q1 & 0xFF) << 8) |
                       ((uint32_t)(q2 & 0xFF) << 16) | ((uint32_t)(q3 & 0xFF) << 24);
    *(uint32_t*)(qr + k0) = p;
  }
}

// ---------------- compact outlier indices (ordered, single block) ----------------
__global__ __launch_bounds__(256) void k_compact(const int* __restrict__ mask,
                                                 uint8_t* __restrict__ bitbytes,
                                                 int* __restrict__ ind,
                                                 int* __restrict__ count) {
  const int t = threadIdx.x;
  int local[16];
  int cnt = 0;
  uint32_t bits = 0;
#pragma unroll
  for (int j = 0; j < 16; ++j) {
    const int k = t * 16 + j;
    if (mask[k]) { bits |= (1u << j); local[cnt++] = k; }
  }
  bitbytes[2 * t]     = (uint8_t)(bits & 0xFF);
  bitbytes[2 * t + 1] = (uint8_t)((bits >> 8) & 0xFF);

  const int lane = t & 63, wid = t >> 6;
  int incl = cnt;
  for (int off = 1; off < 64; off <<= 1) {
    int o = __shfl_up(incl, off);
    if (lane >= off) incl += o;
  }
  __shared__ int wsum[4];
  if (lane == 63) wsum[wid] = incl;
  __syncthreads();
  int base = 0;
  for (int i = 0; i < wid; ++i) base += wsum[i];
  const int excl = base + incl - cnt;
  for (int j = 0; j < cnt; ++j) {
    const int pos = excl + j;
    if (pos < NO_CAP) ind[pos] = local[j];
  }
  if (t == 255) {
    const int tot = excl + cnt;
    *count = tot > NO_CAP ? NO_CAP : tot;
  }
}

// ---------------- fused: weight quant (blocks 0..N/4-1)  +  xo gather (rest) ----
__global__ __launch_bounds__(256) void k_quant_w_gather(const float* __restrict__ w,
                                                        const float* __restrict__ x,
                                                        const uint8_t* __restrict__ bitbytes,
                                                        const int* __restrict__ ind,
                                                        const int* __restrict__ count,
                                                        int8_t* __restrict__ qw,
                                                        float* __restrict__ scale_col,
                                                        float* __restrict__ wo,
                                                        float* __restrict__ xo,
                                                        int nwb) {
  if ((int)blockIdx.x >= nwb) {
    // xo gather: thread per (m, j)
    const int idx = (blockIdx.x - nwb) * 256 + threadIdx.x;   // over M * NO_CAP
    const int m = idx >> 6, j = idx & 63;
    const int cnt = *count;
    float val = 0.0f;
    if (j < cnt) val = x[(size_t)m * K_TOT + ind[j]];
    xo[(size_t)m * NO_CAP + j] = val;
    return;
  }
  const int lane = threadIdx.x & 63;
  const int wid  = threadIdx.x >> 6;
  const int n = blockIdx.x * 4 + wid;
  const float* wr_ = w + (size_t)n * K_TOT;

  float4 v[16];
  float amax = 0.0f;
#pragma unroll
  for (int it = 0; it < 16; ++it) {
    const int k0 = it * 256 + lane * 4;
    v[it] = *(const float4*)(wr_ + k0);
    const uint32_t b = (uint32_t)(bitbytes[k0 >> 3] >> (k0 & 7));
    if (b & 1u) v[it].x = 0.0f;
    if (b & 2u) v[it].y = 0.0f;
    if (b & 4u) v[it].z = 0.0f;
    if (b & 8u) v[it].w = 0.0f;
    amax = fmaxf(amax, fmaxf(fmaxf(fabsf(v[it].x), fabsf(v[it].y)),
                             fmaxf(fabsf(v[it].z), fabsf(v[it].w))));
  }
#pragma unroll
  for (int off = 32; off > 0; off >>= 1)
    amax = fmaxf(amax, __shfl_xor(amax, off));

  float s = amax / 127.0f;
  s = __half2float(__float2half_rn(s));
  s = fmaxf(s, 1e-8f);
  if (lane == 0) scale_col[n] = s;

  int8_t* qr = qw + (size_t)n * K_TOT;
#pragma unroll
  for (int it = 0; it < 16; ++it) {
    const int k0 = it * 256 + lane * 4;
    const int q0 = (int)rintf(fminf(fmaxf(v[it].x / s, -128.0f), 127.0f));
    const int q1 = (int)rintf(fminf(fmaxf(v[it].y / s, -128.0f), 127.0f));
    const int q2 = (int)rintf(fminf(fmaxf(v[it].z / s, -128.0f), 127.0f));
    const int q3 = (int)rintf(fminf(fmaxf(v[it].w / s, -128.0f), 127.0f));
    const uint32_t p = (uint32_t)(q0 & 0xFF) | ((uint32_t)(q1 & 0xFF) << 8) |
                       ((uint32_t)(q2 & 0xFF) << 16) | ((uint32_t)(q3 & 0xFF) << 24);
    *(uint32_t*)(qr + k0) = p;
  }

  const int cnt = *count;
  if (lane < NO_CAP) {
    float val = 0.0f;
    if (lane < cnt) val = wr_[ind[lane]];
    wo[(size_t)n * NO_CAP + lane] = val;
  }
}

// =====================================================================
// int8 GEMM: 256x256 tile, BK=128B, 4-phase/K-tile, one barrier/phase —
// r13 exact (session best: GEMM ~172us, total 224us). Reads front-loaded
// p0/p1, stages back-loaded p2/p3 into current-parity buffer, vmcnt(8)
// at p3 (0 only in 2-tile tail). 8x8 supertile dispatch map (FETCH
// 316->137MB). NT epilogue stores. Register budget: acc 128 AGPR +
// ~128 arch VGPR x 2 waves/SIMD = full 512-reg unified file — 4
// waves/SIMD is structurally impossible (r15 spill, r16 spill+barrier
// loss both measured). Staged flow 1.05 GB at ~6.1 TB/s = within 3% of
// the chip's measured achievable vmem BW (m13: 6.29 TB/s).
// =====================================================================
#define STAGE_A(h, kt, bufb) do { \
  __builtin_amdgcn_global_load_lds((const GAS void*)(qx + gAoff[0] + (size_t)(h)*128*K_TOT + (size_t)(kt)*128), \
      (LAS void*)(smem + (bufb)*32768 + (h)*16384 + ldsOff0), 16, 0, 0); \
  __builtin_amdgcn_global_load_lds((const GAS void*)(qx + gAoff[1] + (size_t)(h)*128*K_TOT + (size_t)(kt)*128), \
      (LAS void*)(smem + (bufb)*32768 + (h)*16384 + ldsOff1), 16, 0, 0); \
} while (0)

#define STAGE_B(h, kt, bufb) do { \
  __builtin_amdgcn_global_load_lds((const GAS void*)(qw + gBoff[0] + (size_t)(h)*128*K_TOT + (size_t)(kt)*128), \
      (LAS void*)(smem + 65536 + (bufb)*32768 + (h)*16384 + ldsOff0), 16, 0, 0); \
  __builtin_amdgcn_global_load_lds((const GAS void*)(qw + gBoff[1] + (size_t)(h)*128*K_TOT + (size_t)(kt)*128), \
      (LAS void*)(smem + 65536 + (bufb)*32768 + (h)*16384 + ldsOff1), 16, 0, 0); \
} while (0)

#define LDA(mq, bufb) do { \
  _Pragma("unroll") for (int i_ = 0; i_ < 4; ++i_) \
  _Pragma("unroll") for (int ks_ = 0; ks_ < 2; ++ks_) \
    a[(mq)*4 + i_][ks_] = *(const v4i*)(smem + aHalfBase + (bufb)*32768 + ((mq)*4 + i_)*2048 + ks_*1024 + rcSwz); \
} while (0)

#define LDB(dst, nq, bufb) do { \
  _Pragma("unroll") for (int i_ = 0; i_ < 2; ++i_) \
  _Pragma("unroll") for (int ks_ = 0; ks_ < 2; ++ks_) \
    dst[i_][ks_] = *(const v4i*)(smem + bHalfBase + (bufb)*32768 + (bColBlk + (nq)*2 + i_)*2048 + ks_*1024 + rcSwz); \
} while (0)

#define MM(mq, nq, bsrc) do { \
  _Pragma("unroll") for (int i_ = 0; i_ < 4; ++i_) \
  _Pragma("unroll") for (int j_ = 0; j_ < 2; ++j_) \
  _Pragma("unroll") for (int ks_ = 0; ks_ < 2; ++ks_) \
    acc[(mq)*4 + i_][(nq)*2 + j_] = __builtin_amdgcn_mfma_i32_16x16x64_i8( \
        a[(mq)*4 + i_][ks_], bsrc[j_][ks_], acc[(mq)*4 + i_][(nq)*2 + j_], 0, 0, 0); \
} while (0)

#define BAR() __builtin_amdgcn_s_barrier()
#define PHASE_MFMA(mq, nq, bsrc) do { \
  BAR(); \
  __builtin_amdgcn_s_setprio(1); \
  MM(mq, nq, bsrc); \
  __builtin_amdgcn_s_setprio(0); \
} while (0)

__global__ __launch_bounds__(512, 2) void k_gemm8(const int8_t* __restrict__ qx,
                                                  const int8_t* __restrict__ qw,
                                                  const float* __restrict__ scale_row,
                                                  const float* __restrict__ scale_col,
                                                  const float* __restrict__ xo,
                                                  const float* __restrict__ wo,
                                                  const int* __restrict__ countp,
                                                  const float* __restrict__ bias,
                                                  float* __restrict__ out) {
  extern __shared__ int8_t smem[];
  constexpr int NT = K_TOT / 128;   // 32 K-tiles

  const int t = threadIdx.x;
  const int lane = t & 63;
  const int wid = t >> 6;
  const int wm = wid >> 2;          // 0..1
  const int wn = wid & 3;           // 0..3

  // 8x8 supertile dispatch mapping (bijective: nbx=32, nby=16, both %8==0)
  const int nbx = gridDim.x;                       // M/256 (32)
  const int o = blockIdx.y * nbx + blockIdx.x;     // dispatch order
  const int gm_cnt = nbx >> 3;                     // supergroups along m (4)
  const int g = o >> 6, r = o & 63;
  const int bm0 = (((g % gm_cnt) << 3) + (r & 7)) * 256;
  const int bn0 = (((g / gm_cnt) << 3) + (r >> 3)) * 256;

  // staging addresses: thread covers 16B chunk f = l*512 + t of a 16KB half-tile
  size_t gAoff[2], gBoff[2];
#pragma unroll
  for (int l = 0; l < 2; ++l) {
    const int f = l * 512 + t;
    const int rb = f >> 7, kb = (f >> 6) & 1, rr_ = (f >> 2) & 15, c16 = f & 3;
    const int c16s = c16 ^ ((rr_ & 8) ? 2 : 0);          // pre-swizzled source chunk
    const int rowInHalf = rb * 16 + rr_;
    const int colByte = kb * 64 + c16s * 16;
    gAoff[l] = (size_t)(bm0 + rowInHalf) * K_TOT + colByte;
    gBoff[l] = (size_t)(bn0 + rowInHalf) * K_TOT + colByte;
  }
  const int ldsOff0 = wid * 1024;          // wave-uniform; lane*16 added by HW
  const int ldsOff1 = 8192 + wid * 1024;

  // ds_read fragment addressing (swizzled)
  const int rr = lane & 15;
  const int rcSwz = rr * 64 + (((lane >> 4) * 16) ^ ((lane & 8) ? 32 : 0));
  const int aHalfBase = wm * 16384;
  const int bHalfBase = 65536 + (wn >> 1) * 16384;
  const int bColBlk = (wn & 1) * 4;

  v4i acc[8][4];
#pragma unroll
  for (int i = 0; i < 8; ++i)
#pragma unroll
    for (int j = 0; j < 4; ++j) acc[i][j] = (v4i){0, 0, 0, 0};
  v4i a[8][2], b0[2][2], b1[2][2];

  // prologue: stage tile0 -> buf0, tile1 -> buf1; wait tile0 complete (8 left)
  STAGE_A(0, 0, 0);
  STAGE_A(1, 0, 0);
  STAGE_B(0, 0, 0);
  STAGE_B(1, 0, 0);
  STAGE_A(0, 1, 1);
  STAGE_A(1, 1, 1);
  STAGE_B(0, 1, 1);
  STAGE_B(1, 1, 1);
  asm volatile("s_waitcnt vmcnt(8)" ::: "memory");
  BAR();

#pragma unroll 2
  for (int t0 = 0; t0 < NT; ++t0) {
    const int buf = t0 & 1;
    // ---- phase 0: read a03,b0 ; Q(0,0) ----
    LDA(0, buf);
    LDB(b0, 0, buf);
    PHASE_MFMA(0, 0, b0);
    // ---- phase 1: read b1,a47 ; Q(0,1) ----
    LDB(b1, 1, buf);
    LDA(1, buf);
    PHASE_MFMA(0, 1, b1);
    // ---- phase 2: stage A(t+2) -> same-parity buffer (reads done @p1) ; Q(1,1) ----
    if (t0 + 2 < NT) {
      STAGE_A(0, t0 + 2, buf);
      STAGE_A(1, t0 + 2, buf);
    }
    PHASE_MFMA(1, 1, b1);
    // ---- phase 3: stage B(t+2) ; retire tile t+1 (vmcnt 8) ; Q(1,0) ----
    if (t0 + 2 < NT) {
      STAGE_B(0, t0 + 2, buf);
      STAGE_B(1, t0 + 2, buf);
    }
    if (t0 < NT - 2) {
      asm volatile("s_waitcnt vmcnt(8)" ::: "memory");
    } else {
      asm volatile("s_waitcnt vmcnt(0)" ::: "memory");
    }
    PHASE_MFMA(1, 0, b0);
  }

  // ---- epilogue: y = acc*sr*sc + outlier_dot + bias, rounded to fp16 precision ----
  const int cnt = *countp;
  const int col = lane & 15;
  const int row4 = (lane >> 4) * 4;

  float scn[4], bzn[4];
  int nn[4];
#pragma unroll
  for (int ni = 0; ni < 4; ++ni) {
    const int n = bn0 + wn * 64 + ni * 16 + col;
    nn[ni] = n;
    scn[ni] = scale_col[n];
    bzn[ni] = bias[n];
  }

  if (cnt <= 8) {
    float wv[4][8];
#pragma unroll
    for (int ni = 0; ni < 4; ++ni)
#pragma unroll
      for (int j = 0; j < 8; ++j) wv[ni][j] = wo[(size_t)nn[ni] * NO_CAP + j];
#pragma unroll
    for (int mi = 0; mi < 8; ++mi) {
#pragma unroll
      for (int r2 = 0; r2 < 4; ++r2) {
        const int m = bm0 + wm * 128 + mi * 16 + row4 + r2;
        const float srm = scale_row[m];
        float xv[8];
#pragma unroll
        for (int j = 0; j < 8; ++j) xv[j] = xo[(size_t)m * NO_CAP + j];
#pragma unroll
        for (int ni = 0; ni < 4; ++ni) {
          float y = (float)acc[mi][ni][r2] * srm * scn[ni];
#pragma unroll
          for (int j = 0; j < 8; ++j) y += xv[j] * wv[ni][j];
          y += bzn[ni];
          __builtin_nontemporal_store(__half2float(__float2half_rn(y)),
                                      &out[(size_t)m * N_TOT + nn[ni]]);
        }
      }
    }
  } else {
#pragma unroll
    for (int mi = 0; mi < 8; ++mi) {
#pragma unroll
      for (int r2 = 0; r2 < 4; ++r2) {
        const int m = bm0 + wm * 128 + mi * 16 + row4 + r2;
        const float srm = scale_row[m];
#pragma unroll
        for (int ni = 0; ni < 4; ++ni) {
          float y = (float)acc[mi][ni][r2] * srm * scn[ni];
          for (int j = 0; j < cnt; ++j)
            y += xo[(size_t)m * NO_CAP + j] * wo[(size_t)nn[ni] * NO_CAP + j];
          y += bzn[ni];
          __builtin_nontemporal_store(__half2float(__float2half_rn(y)),
                                      &out[(size_t)m * N_TOT + nn[ni]]);
        }
      }
    }
  }
}

extern "C" void kernel_launch(void* const* d_in, const int* in_sizes, int n_in,
                              void* d_out, int out_size, void* d_ws, size_t ws_size,
                              hipStream_t stream) {
  const float* x    = (const float*)d_in[0];
  const float* w    = (const float*)d_in[1];
  const float* bias = (const float*)d_in[2];
  float* out        = (float*)d_out;

  const int M = in_sizes[0] / K_TOT;   // 8192 for B=4,S=2048

  char* ws = (char*)d_ws;
  const size_t OFF_SR   = 0;
  const size_t OFF_SC   = OFF_SR + sizeof(float) * (size_t)M;
  const size_t OFF_MASK = OFF_SC + sizeof(float) * (size_t)N_TOT;
  const size_t OFF_IND  = OFF_MASK + sizeof(int) * (size_t)K_TOT;
  const size_t OFF_CNT  = OFF_IND + sizeof(int) * (size_t)NO_CAP;
  const size_t OFF_BB   = OFF_CNT + 256;
  const size_t OFF_XO   = (OFF_BB + (size_t)(K_TOT / 8) + 255) & ~(size_t)255;
  const size_t OFF_WO   = OFF_XO + sizeof(float) * (size_t)M * NO_CAP;
  const size_t OFF_QX   = (OFF_WO + sizeof(float) * (size_t)N_TOT * NO_CAP + 255) & ~(size_t)255;
  const size_t OFF_QW   = OFF_QX + (size_t)M * K_TOT;

  float* scale_row  = (float*)(ws + OFF_SR);
  float* scale_col  = (float*)(ws + OFF_SC);
  int* mask         = (int*)(ws + OFF_MASK);
  int* ind          = (int*)(ws + OFF_IND);
  int* count        = (int*)(ws + OFF_CNT);
  uint8_t* bitbytes = (uint8_t*)(ws + OFF_BB);
  float* xo         = (float*)(ws + OFF_XO);
  float* wo         = (float*)(ws + OFF_WO);
  int8_t* qx        = (int8_t*)(ws + OFF_QX);
  int8_t* qw        = (int8_t*)(ws + OFF_QW);

  // allow 128 KiB dynamic LDS for the GEMM
  hipFuncSetAttribute((const void*)k_gemm8,
                      hipFuncAttributeMaxDynamicSharedMemorySize, 131072);

  // mask zeroing via memset node (replaces k_init launch)
  hipMemsetAsync(mask, 0, sizeof(int) * (size_t)K_TOT, stream);
  hipLaunchKernelGGL(k_quant_x, dim3(M / 4), dim3(256), 0, stream, x, qx, scale_row, mask);
  hipLaunchKernelGGL(k_compact, dim3(1), dim3(256), 0, stream, mask, bitbytes, ind, count);
  const int nwb = N_TOT / 4;                         // 1024 weight blocks
  const int ngb = (M * NO_CAP) / 256;                // 2048 gather blocks
  hipLaunchKernelGGL(k_quant_w_gather, dim3(nwb + ngb), dim3(256), 0, stream,
                     w, x, bitbytes, ind, count, qw, scale_col, wo, xo, nwb);
  hipLaunchKernelGGL(k_gemm8, dim3(M / 256, N_TOT / 256), dim3(512), 131072, stream,
                     qx, qw, scale_row, scale_col, xo, wo, count, bias, out);
}